// Round 1
// baseline (419.377 us; speedup 1.0000x reference)
//
#include <hip/hip_runtime.h>

// SE(3) transform of 16M homogeneous points: out = M @ x, M = se3_exp(w,v,theta).
// Memory-bound: 256 MB read + 256 MB write. Strategy: one pass, float4 per row,
// matrix built per-thread in registers (scalar inputs broadcast from L1/L2).

__global__ __launch_bounds__(256) void se3_transform_kernel(
    const float* __restrict__ x,
    const float* __restrict__ w,
    const float* __restrict__ v,
    const float* __restrict__ th_p,
    float* __restrict__ out,
    int N)
{
    // ---- Build the 4x4 SE3 matrix (rows 0..2; row 3 = [0,0,0,1]) ----
    const float w0 = w[0], w1 = w[1], w2 = w[2];
    const float v0 = v[0], v1 = v[1], v2 = v[2];
    const float th = th_p[0];
    const float s = sinf(th);
    const float c = cosf(th);
    const float omc = 1.0f - c;   // (1 - cos)
    const float tms = th - s;     // (theta - sin)

    // K = skew(w); KK = K @ K
    const float kk00 = -(w1 * w1 + w2 * w2);
    const float kk11 = -(w0 * w0 + w2 * w2);
    const float kk22 = -(w0 * w0 + w1 * w1);
    const float kk01 = w0 * w1;
    const float kk02 = w0 * w2;
    const float kk12 = w1 * w2;

    // R = I + s*K + (1-c)*KK
    const float r00 = 1.0f + omc * kk00;
    const float r01 = -s * w2 + omc * kk01;
    const float r02 =  s * w1 + omc * kk02;
    const float r10 =  s * w2 + omc * kk01;
    const float r11 = 1.0f + omc * kk11;
    const float r12 = -s * w0 + omc * kk12;
    const float r20 = -s * w1 + omc * kk02;
    const float r21 =  s * w0 + omc * kk12;
    const float r22 = 1.0f + omc * kk22;

    // V = theta*I + (1-c)*K + (theta-s)*KK ; t = V @ v
    const float V00 = th + tms * kk00;
    const float V01 = -omc * w2 + tms * kk01;
    const float V02 =  omc * w1 + tms * kk02;
    const float V10 =  omc * w2 + tms * kk01;
    const float V11 = th + tms * kk11;
    const float V12 = -omc * w0 + tms * kk12;
    const float V20 = -omc * w1 + tms * kk02;
    const float V21 =  omc * w0 + tms * kk12;
    const float V22 = th + tms * kk22;

    const float t0 = V00 * v0 + V01 * v1 + V02 * v2;
    const float t1 = V10 * v0 + V11 * v1 + V12 * v2;
    const float t2 = V20 * v0 + V21 * v1 + V22 * v2;

    // ---- Main body: 4 columns per thread via float4 ----
    const int n4 = N >> 2;
    const int i4 = blockIdx.x * blockDim.x + threadIdx.x;

    if (i4 < n4) {
        const float4* x0p = (const float4*)(x);
        const float4* x1p = (const float4*)(x + (size_t)N);
        const float4* x2p = (const float4*)(x + 2 * (size_t)N);
        const float4* x3p = (const float4*)(x + 3 * (size_t)N);

        const float4 a = x0p[i4];
        const float4 b = x1p[i4];
        const float4 e = x2p[i4];
        const float4 d = x3p[i4];

        float4 o0, o1, o2;
        o0.x = r00 * a.x + r01 * b.x + r02 * e.x + t0 * d.x;
        o0.y = r00 * a.y + r01 * b.y + r02 * e.y + t0 * d.y;
        o0.z = r00 * a.z + r01 * b.z + r02 * e.z + t0 * d.z;
        o0.w = r00 * a.w + r01 * b.w + r02 * e.w + t0 * d.w;

        o1.x = r10 * a.x + r11 * b.x + r12 * e.x + t1 * d.x;
        o1.y = r10 * a.y + r11 * b.y + r12 * e.y + t1 * d.y;
        o1.z = r10 * a.z + r11 * b.z + r12 * e.z + t1 * d.z;
        o1.w = r10 * a.w + r11 * b.w + r12 * e.w + t1 * d.w;

        o2.x = r20 * a.x + r21 * b.x + r22 * e.x + t2 * d.x;
        o2.y = r20 * a.y + r21 * b.y + r22 * e.y + t2 * d.y;
        o2.z = r20 * a.z + r21 * b.z + r22 * e.z + t2 * d.z;
        o2.w = r20 * a.w + r21 * b.w + r22 * e.w + t2 * d.w;

        ((float4*)(out))[i4] = o0;
        ((float4*)(out + (size_t)N))[i4] = o1;
        ((float4*)(out + 2 * (size_t)N))[i4] = o2;
        ((float4*)(out + 3 * (size_t)N))[i4] = d;  // bottom row of M is [0,0,0,1]
    }

    // ---- Tail (N % 4 != 0); no-op for N = 16M ----
    const int tail = N & 3;
    if (blockIdx.x == 0 && (int)threadIdx.x < tail) {
        const int j = (N & ~3) + (int)threadIdx.x;
        const float a = x[j];
        const float b = x[(size_t)N + j];
        const float e = x[2 * (size_t)N + j];
        const float d = x[3 * (size_t)N + j];
        out[j]                 = r00 * a + r01 * b + r02 * e + t0 * d;
        out[(size_t)N + j]     = r10 * a + r11 * b + r12 * e + t1 * d;
        out[2 * (size_t)N + j] = r20 * a + r21 * b + r22 * e + t2 * d;
        out[3 * (size_t)N + j] = d;
    }
}

extern "C" void kernel_launch(void* const* d_in, const int* in_sizes, int n_in,
                              void* d_out, int out_size, void* d_ws, size_t ws_size,
                              hipStream_t stream) {
    const float* x  = (const float*)d_in[0];   // [4, N] row-major
    const float* w  = (const float*)d_in[1];   // [3]
    const float* v  = (const float*)d_in[2];   // [3]
    const float* th = (const float*)d_in[3];   // [1]
    float* out = (float*)d_out;                // [4, N]

    const int N = in_sizes[0] / 4;
    const int n4 = N / 4;
    int blocks = (n4 + 255) / 256;
    if (blocks < 1) blocks = 1;

    se3_transform_kernel<<<blocks, 256, 0, stream>>>(x, w, v, th, out, N);
}

// Round 3
// 409.055 us; speedup vs baseline: 1.0252x; 1.0252x over previous
//
#include <hip/hip_runtime.h>
#include <math.h>

// out = M @ x with M = se3_exp(w, v, theta), x: [4, N] fp32 row-major, N = 16M.
// Memory-bound streaming: 256 MB read + 256 MB write -> ~81 us floor at 6.3 TB/s.
//
// Two-launch structure:
//   k1 (1 thread): build the 12 matrix coefficients (rows 0..2 of M) into d_ws.
//      Keeps sinf/cosf (ocml code, register pressure) out of the hot kernel.
//   k2: pure streaming transform. M read at uniform offsets -> SGPRs via s_load;
//      nontemporal 16B loads/stores (touch-once streams, skip cache allocate).
//
// Note: __builtin_nontemporal_* requires a NATIVE clang vector type, not HIP's
// float4 class. Use ext_vector_type(4).

typedef float f32x4 __attribute__((ext_vector_type(4)));

__global__ void se3_build_kernel(const float* __restrict__ w,
                                 const float* __restrict__ v,
                                 const float* __restrict__ th_p,
                                 float* __restrict__ M /* 12 floats in ws */) {
    if (threadIdx.x != 0 || blockIdx.x != 0) return;

    const float w0 = w[0], w1 = w[1], w2 = w[2];
    const float v0 = v[0], v1 = v[1], v2 = v[2];
    const float th = th_p[0];
    const float s = sinf(th);
    const float c = cosf(th);
    const float omc = 1.0f - c;
    const float tms = th - s;

    const float kk00 = -(w1 * w1 + w2 * w2);
    const float kk11 = -(w0 * w0 + w2 * w2);
    const float kk22 = -(w0 * w0 + w1 * w1);
    const float kk01 = w0 * w1;
    const float kk02 = w0 * w2;
    const float kk12 = w1 * w2;

    // R = I + s*K + (1-c)*K^2
    const float r00 = 1.0f + omc * kk00;
    const float r01 = -s * w2 + omc * kk01;
    const float r02 =  s * w1 + omc * kk02;
    const float r10 =  s * w2 + omc * kk01;
    const float r11 = 1.0f + omc * kk11;
    const float r12 = -s * w0 + omc * kk12;
    const float r20 = -s * w1 + omc * kk02;
    const float r21 =  s * w0 + omc * kk12;
    const float r22 = 1.0f + omc * kk22;

    // V = th*I + (1-c)*K + (th-s)*K^2 ; t = V @ v
    const float V00 = th + tms * kk00;
    const float V01 = -omc * w2 + tms * kk01;
    const float V02 =  omc * w1 + tms * kk02;
    const float V10 =  omc * w2 + tms * kk01;
    const float V11 = th + tms * kk11;
    const float V12 = -omc * w0 + tms * kk12;
    const float V20 = -omc * w1 + tms * kk02;
    const float V21 =  omc * w0 + tms * kk12;
    const float V22 = th + tms * kk22;

    M[0]  = r00; M[1]  = r01; M[2]  = r02; M[3]  = V00 * v0 + V01 * v1 + V02 * v2;
    M[4]  = r10; M[5]  = r11; M[6]  = r12; M[7]  = V10 * v0 + V11 * v1 + V12 * v2;
    M[8]  = r20; M[9]  = r21; M[10] = r22; M[11] = V20 * v0 + V21 * v1 + V22 * v2;
}

__global__ __launch_bounds__(256) void se3_transform_kernel(
    const float* __restrict__ x,
    const float* __restrict__ M,
    float* __restrict__ out,
    int N)
{
    // Uniform constant-offset reads -> scalar loads into SGPRs.
    const float r00 = M[0], r01 = M[1], r02 = M[2],  t0 = M[3];
    const float r10 = M[4], r11 = M[5], r12 = M[6],  t1 = M[7];
    const float r20 = M[8], r21 = M[9], r22 = M[10], t2 = M[11];

    const int n4 = N >> 2;
    const int i4 = blockIdx.x * blockDim.x + threadIdx.x;

    if (i4 < n4) {
        const f32x4* x0p = (const f32x4*)(x);
        const f32x4* x1p = (const f32x4*)(x + (size_t)N);
        const f32x4* x2p = (const f32x4*)(x + 2 * (size_t)N);
        const f32x4* x3p = (const f32x4*)(x + 3 * (size_t)N);

        const f32x4 a = __builtin_nontemporal_load(x0p + i4);
        const f32x4 b = __builtin_nontemporal_load(x1p + i4);
        const f32x4 e = __builtin_nontemporal_load(x2p + i4);
        const f32x4 d = __builtin_nontemporal_load(x3p + i4);

        f32x4 o0, o1, o2;
        o0 = r00 * a + r01 * b + r02 * e + t0 * d;
        o1 = r10 * a + r11 * b + r12 * e + t1 * d;
        o2 = r20 * a + r21 * b + r22 * e + t2 * d;

        __builtin_nontemporal_store(o0, (f32x4*)(out) + i4);
        __builtin_nontemporal_store(o1, (f32x4*)(out + (size_t)N) + i4);
        __builtin_nontemporal_store(o2, (f32x4*)(out + 2 * (size_t)N) + i4);
        __builtin_nontemporal_store(d,  (f32x4*)(out + 3 * (size_t)N) + i4);  // row 3 of M = [0,0,0,1]
    }

    // Tail for N % 4 != 0 (no-op at N = 16M).
    const int tail = N & 3;
    if (blockIdx.x == 0 && (int)threadIdx.x < tail) {
        const int j = (N & ~3) + (int)threadIdx.x;
        const float a = x[j];
        const float b = x[(size_t)N + j];
        const float e = x[2 * (size_t)N + j];
        const float d = x[3 * (size_t)N + j];
        out[j]                 = r00 * a + r01 * b + r02 * e + t0 * d;
        out[(size_t)N + j]     = r10 * a + r11 * b + r12 * e + t1 * d;
        out[2 * (size_t)N + j] = r20 * a + r21 * b + r22 * e + t2 * d;
        out[3 * (size_t)N + j] = d;
    }
}

extern "C" void kernel_launch(void* const* d_in, const int* in_sizes, int n_in,
                              void* d_out, int out_size, void* d_ws, size_t ws_size,
                              hipStream_t stream) {
    const float* x  = (const float*)d_in[0];   // [4, N]
    const float* w  = (const float*)d_in[1];   // [3]
    const float* v  = (const float*)d_in[2];   // [3]
    const float* th = (const float*)d_in[3];   // [1]
    float* out = (float*)d_out;                // [4, N]
    float* M   = (float*)d_ws;                 // 12 floats

    const int N = in_sizes[0] / 4;
    const int n4 = N / 4;
    int blocks = (n4 + 255) / 256;
    if (blocks < 1) blocks = 1;

    se3_build_kernel<<<1, 64, 0, stream>>>(w, v, th, M);
    se3_transform_kernel<<<blocks, 256, 0, stream>>>(x, M, out, N);
}